// Round 2
// baseline (486.458 us; speedup 1.0000x reference)
//
#include <hip/hip_runtime.h>
#include <hip/hip_bf16.h>
#include <stdint.h>

#define BB 32
#define TT 4096
#define DD 64
#define SS 128
#define HH 512

#define CH_L 256
#define CH_W 64
#define NCHUNK (TT / CH_L)

typedef __attribute__((ext_vector_type(4))) float f32x4;
typedef __attribute__((ext_vector_type(8))) short s16x8;
typedef __attribute__((ext_vector_type(4))) short s16x4;

__device__ __forceinline__ ushort f2bfu(float x) {
    uint32_t b = __float_as_uint(x);
    uint32_t r = (b + 0x7FFFu + ((b >> 16) & 1u)) >> 16;
    return (ushort)r;
}
__device__ __forceinline__ float bfu2f(ushort u) {
    return __uint_as_float(((uint32_t)u) << 16);
}

// ---------------------------------------------------------------------------
// Prep: PfT[k][i] = softmax_row_i(trans)[k]; PbT[s][i] = softmax_col_i(trans)[s]
// 256 WGs of 128: wg<128 -> row softmax (forward), wg>=128 -> col softmax (bwd)
// ---------------------------------------------------------------------------
__global__ __launch_bounds__(128) void prep_trans(const float* __restrict__ tr,
                                                  float* __restrict__ PfT,
                                                  float* __restrict__ PbT) {
    int i = blockIdx.x & 127;
    int back = blockIdx.x >> 7;
    int j = threadIdx.x;
    float v = back ? tr[j * SS + i] : tr[i * SS + j];
    __shared__ float sh[4];
    float mx = v;
#pragma unroll
    for (int off = 32; off; off >>= 1) mx = fmaxf(mx, __shfl_xor(mx, off));
    if ((threadIdx.x & 63) == 0) sh[threadIdx.x >> 6] = mx;
    __syncthreads();
    mx = fmaxf(sh[0], sh[1]);
    float e = __expf(v - mx);
    float ssum = e;
#pragma unroll
    for (int off = 32; off; off >>= 1) ssum += __shfl_xor(ssum, off);
    if ((threadIdx.x & 63) == 0) sh[2 + (threadIdx.x >> 6)] = ssum;
    __syncthreads();
    float out = e / (sh[2] + sh[3]);
    if (back) PbT[j * SS + i] = out;
    else      PfT[j * SS + i] = out;
}

// ---------------------------------------------------------------------------
// Convert w1 (512x64) and w2 (128x512) fp32 -> bf16
// ---------------------------------------------------------------------------
__global__ void conv_w(const float* __restrict__ w1, const float* __restrict__ w2,
                       ushort* __restrict__ w1b, ushort* __restrict__ w2b) {
    int i = blockIdx.x * 256 + threadIdx.x;
    const int N1 = HH * DD;            // 32768
    const int N2 = SS * HH;            // 65536
    if (i < N1) w1b[i] = f2bfu(w1[i]);
    else if (i < N1 + N2) w2b[i - N1] = f2bfu(w2[i - N1]);
}

// ---------------------------------------------------------------------------
// Fused MLP: emit[b][t][s] (bf16) = relu(obs@W1^T + b1) @ W2^T + b2
// ---------------------------------------------------------------------------
#define MLP_ROWS 32
__global__ __launch_bounds__(256) void mlp_kernel(
    const float* __restrict__ obs, const ushort* __restrict__ w1b,
    const ushort* __restrict__ w2b, const float* __restrict__ b1,
    const float* __restrict__ b2, ushort* __restrict__ emitb) {
    __shared__ __align__(16) ushort Alds[MLP_ROWS][72];   // 64 k + pad
    __shared__ __align__(16) ushort Hlds[MLP_ROWS][520];  // 512 k + pad

    int wg = blockIdx.x;                  // 32 * 128 = 4096
    int bb = wg >> 7;
    int t0 = (wg & 127) * MLP_ROWS;
    int tid = threadIdx.x;
    int lane = tid & 63, wv = tid >> 6;
    int lhi = lane >> 4, llo = lane & 15;

    {
        int r = tid >> 3, c0 = (tid & 7) * 8;
        const float* src = obs + ((size_t)bb * TT + t0 + r) * DD + c0;
        float4 v0 = *(const float4*)(src);
        float4 v1 = *(const float4*)(src + 4);
        Alds[r][c0 + 0] = f2bfu(v0.x); Alds[r][c0 + 1] = f2bfu(v0.y);
        Alds[r][c0 + 2] = f2bfu(v0.z); Alds[r][c0 + 3] = f2bfu(v0.w);
        Alds[r][c0 + 4] = f2bfu(v1.x); Alds[r][c0 + 5] = f2bfu(v1.y);
        Alds[r][c0 + 6] = f2bfu(v1.z); Alds[r][c0 + 7] = f2bfu(v1.w);
    }
    __syncthreads();

    f32x4 acc1[2][8];
#pragma unroll
    for (int mi = 0; mi < 2; ++mi)
#pragma unroll
        for (int ni = 0; ni < 8; ++ni) acc1[mi][ni] = (f32x4){0.f, 0.f, 0.f, 0.f};
    int nw0 = wv * 128;
#pragma unroll
    for (int kt = 0; kt < 2; ++kt) {
        s16x8 af[2];
#pragma unroll
        for (int mi = 0; mi < 2; ++mi)
            af[mi] = *(const s16x8*)(&Alds[mi * 16 + llo][kt * 32 + lhi * 8]);
#pragma unroll
        for (int ni = 0; ni < 8; ++ni) {
            int n = nw0 + ni * 16 + llo;
            s16x8 bf = *(const s16x8*)(w1b + n * DD + kt * 32 + lhi * 8);
#pragma unroll
            for (int mi = 0; mi < 2; ++mi)
                acc1[mi][ni] = __builtin_amdgcn_mfma_f32_16x16x32_bf16(af[mi], bf, acc1[mi][ni], 0, 0, 0);
        }
    }
#pragma unroll
    for (int ni = 0; ni < 8; ++ni) {
        int n = nw0 + ni * 16 + llo;
        float b1v = b1[n];
#pragma unroll
        for (int mi = 0; mi < 2; ++mi) {
#pragma unroll
            for (int r = 0; r < 4; ++r) {
                float hv = fmaxf(acc1[mi][ni][r] + b1v, 0.f);
                Hlds[mi * 16 + lhi * 4 + r][n] = f2bfu(hv);
            }
        }
    }
    __syncthreads();

    f32x4 acc2[2][2];
#pragma unroll
    for (int si = 0; si < 2; ++si)
#pragma unroll
        for (int nt = 0; nt < 2; ++nt) acc2[si][nt] = (f32x4){0.f, 0.f, 0.f, 0.f};
    int s0 = wv * 32;
#pragma unroll
    for (int kt = 0; kt < 16; ++kt) {
        s16x8 hf[2];
#pragma unroll
        for (int nt = 0; nt < 2; ++nt)
            hf[nt] = *(const s16x8*)(&Hlds[nt * 16 + llo][kt * 32 + lhi * 8]);
#pragma unroll
        for (int si = 0; si < 2; ++si) {
            int srow = s0 + si * 16 + llo;
            s16x8 wf = *(const s16x8*)(w2b + srow * HH + kt * 32 + lhi * 8);
#pragma unroll
            for (int nt = 0; nt < 2; ++nt)
                acc2[si][nt] = __builtin_amdgcn_mfma_f32_16x16x32_bf16(wf, hf[nt], acc2[si][nt], 0, 0, 0);
        }
    }
#pragma unroll
    for (int si = 0; si < 2; ++si) {
        int sbase = s0 + si * 16 + lhi * 4;
        float4 b2v = *(const float4*)(b2 + sbase);
#pragma unroll
        for (int nt = 0; nt < 2; ++nt) {
            int tl = nt * 16 + llo;
            ushort* dst = emitb + ((size_t)bb * TT + t0 + tl) * SS + sbase;
            s16x4 pk;
            pk[0] = (short)f2bfu(acc2[si][nt][0] + b2v.x);
            pk[1] = (short)f2bfu(acc2[si][nt][1] + b2v.y);
            pk[2] = (short)f2bfu(acc2[si][nt][2] + b2v.z);
            pk[3] = (short)f2bfu(acc2[si][nt][3] + b2v.w);
            *(s16x4*)dst = pk;
        }
    }
}

// ---------------------------------------------------------------------------
// Chunked scans. One WG = 256 threads = one (b, dir, chunk).
// State s = 32*wave + (lane>>1); half h = lane&1. Each thread holds HALF of
// P^T column s (64 f32 = 16 f32x4 = 64 VGPRs -> no spill under (256,4) cap).
// Pair partials combined with __shfl_xor(q,1). p broadcast via LDS; rescale
// offset m = alpha[state 0] broadcast through the per-step barrier (lag-2).
// ---------------------------------------------------------------------------
__global__ __launch_bounds__(256, 4) void scan_kernel(
    const ushort* __restrict__ emitb, const float* __restrict__ PfT,
    const float* __restrict__ PbT, float* __restrict__ galpha,
    float* __restrict__ gbeta) {
    int wg = blockIdx.x;            // 32 b * 2 dir * 16 chunks = 1024
    int c = wg & (NCHUNK - 1);
    int dir = (wg >> 4) & 1;        // 0 = forward, 1 = backward
    int bb = wg >> 5;
    int tid = threadIdx.x;
    int w = tid >> 6, l = tid & 63;
    int s = w * 32 + (l >> 1);
    int h = l & 1;

    const float* PT = dir ? PbT : PfT;
    f32x4 pc[16];
#pragma unroll
    for (int i = 0; i < 16; ++i) pc[i] = *(const f32x4*)(PT + s * SS + h * 64 + i * 4);

    __shared__ __align__(16) float pbuf[2][SS];
    __shared__ float mslot[2];

    int warm = (dir == 0) ? (c > 0 ? CH_W : 0) : (c < NCHUNK - 1 ? CH_W : 0);
    int nstep = CH_L + warm;
    int tfirst = (dir == 0) ? c * CH_L - warm : c * CH_L + CH_L - 1 + warm;
    intptr_t estep = (dir == 0) ? (intptr_t)SS : -(intptr_t)SS;

    const ushort* erow = emitb + ((size_t)bb * TT + tfirst) * SS + s;
    float* outp = ((dir == 0) ? galpha : gbeta) + ((size_t)bb * TT + tfirst) * SS + s;

    float alpha = 0.f, m = 0.f;
    float ecur = bfu2f(erow[0]);
    float enext = bfu2f(erow[estep]);

    for (int v = 0; v < nstep; ++v) {
        float p = __expf(fminf(alpha - m, 60.f));
        if (!h) pbuf[v & 1][s] = p;
        if (tid == 0) mslot[v & 1] = alpha;
        __syncthreads();
        float mnext = mslot[v & 1];                       // alpha_{v-1}[0]
        ushort e2 = erow[(intptr_t)(v + 2) * estep];      // prefetch 2 ahead
        const float* pb = &pbuf[v & 1][h * 64];
        float q0 = 0.f, q1 = 0.f, q2 = 0.f, q3 = 0.f;
#pragma unroll
        for (int i = 0; i < 16; ++i) {
            f32x4 pp = *(const f32x4*)(pb + i * 4);
            q0 = fmaf(pp.x, pc[i].x, q0);
            q1 = fmaf(pp.y, pc[i].y, q1);
            q2 = fmaf(pp.z, pc[i].z, q2);
            q3 = fmaf(pp.w, pc[i].w, q3);
        }
        float qt = (q0 + q1) + (q2 + q3);
        qt += __shfl_xor(qt, 1);
        alpha = m + __logf(qt) + ecur;
        if (v >= warm && !h) outp[(intptr_t)v * estep] = alpha;
        m = mnext;
        ecur = enext;
        enext = bfu2f(e2);
    }
}

// ---------------------------------------------------------------------------
// Combine: out[b][t][s] = softmax_s(alpha + beta)  (log_Z cancels in softmax)
// ---------------------------------------------------------------------------
__global__ __launch_bounds__(256) void combine_kernel(
    const float* __restrict__ galpha, const float* __restrict__ gbeta,
    float* __restrict__ out) {
    int row = blockIdx.x * 4 + (threadIdx.x >> 6);  // b*T + t
    int lane = threadIdx.x & 63;
    size_t base = (size_t)row * SS + lane * 2;
    float2 a = *(const float2*)(galpha + base);
    float2 b = *(const float2*)(gbeta + base);
    float g0 = a.x + b.x, g1 = a.y + b.y;
    float mx = fmaxf(g0, g1);
#pragma unroll
    for (int off = 32; off; off >>= 1) mx = fmaxf(mx, __shfl_xor(mx, off));
    float e0 = __expf(g0 - mx), e1 = __expf(g1 - mx);
    float ssum = e0 + e1;
#pragma unroll
    for (int off = 32; off; off >>= 1) ssum += __shfl_xor(ssum, off);
    float inv = 1.f / ssum;
    float2 o; o.x = e0 * inv; o.y = e1 * inv;
    *(float2*)(out + base) = o;
}

// ---------------------------------------------------------------------------
extern "C" void kernel_launch(void* const* d_in, const int* in_sizes, int n_in,
                              void* d_out, int out_size, void* d_ws, size_t ws_size,
                              hipStream_t stream) {
    const float* obs = (const float*)d_in[0];
    const float* trans = (const float*)d_in[1];
    const float* w1 = (const float*)d_in[2];
    const float* b1 = (const float*)d_in[3];
    const float* w2 = (const float*)d_in[4];
    const float* b2 = (const float*)d_in[5];

    char* ws = (char*)d_ws;
    float* PfT = (float*)(ws);                         // 64 KB
    float* PbT = (float*)(ws + 65536);                 // 64 KB
    ushort* w1b = (ushort*)(ws + 131072);              // 64 KB
    ushort* w2b = (ushort*)(ws + 196608);              // 128 KB
    ushort* emitb = (ushort*)(ws + 327680);            // 32 MB bf16 emissions
    float* galpha = (float*)(ws + 327680 + 33554432);  // 64 MB
    float* gbeta = (float*)(ws + 327680 + 33554432 + 67108864);  // 64 MB

    prep_trans<<<256, 128, 0, stream>>>(trans, PfT, PbT);
    conv_w<<<384, 256, 0, stream>>>(w1, w2, w1b, w2b);
    mlp_kernel<<<BB * (TT / MLP_ROWS), 256, 0, stream>>>(obs, w1b, w2b, b1, b2, emitb);
    scan_kernel<<<BB * 2 * NCHUNK, 256, 0, stream>>>(emitb, PfT, PbT, galpha, gbeta);
    combine_kernel<<<(BB * TT) / 4, 256, 0, stream>>>(galpha, gbeta, (float*)d_out);
}

// Round 3
// 392.089 us; speedup vs baseline: 1.2407x; 1.2407x over previous
//
#include <hip/hip_runtime.h>
#include <hip/hip_bf16.h>
#include <stdint.h>

#define BB 32
#define TT 4096
#define DD 64
#define SS 128
#define HH 512

#define CH_L 256
#define CH_W 64
#define NCHUNK (TT / CH_L)

typedef __attribute__((ext_vector_type(4))) float f32x4;
typedef __attribute__((ext_vector_type(8))) short s16x8;
typedef __attribute__((ext_vector_type(4))) short s16x4;

__device__ __forceinline__ ushort f2bfu(float x) {
    uint32_t b = __float_as_uint(x);
    uint32_t r = (b + 0x7FFFu + ((b >> 16) & 1u)) >> 16;
    return (ushort)r;
}
__device__ __forceinline__ float bfu2f(ushort u) {
    return __uint_as_float(((uint32_t)u) << 16);
}

// ---------------------------------------------------------------------------
// Prep: PfT[k][i] = softmax_row_i(trans)[k]; PbT[s][i] = softmax_col_i(trans)[s]
// ---------------------------------------------------------------------------
__global__ __launch_bounds__(128) void prep_trans(const float* __restrict__ tr,
                                                  float* __restrict__ PfT,
                                                  float* __restrict__ PbT) {
    int i = blockIdx.x & 127;
    int back = blockIdx.x >> 7;
    int j = threadIdx.x;
    float v = back ? tr[j * SS + i] : tr[i * SS + j];
    __shared__ float sh[4];
    float mx = v;
#pragma unroll
    for (int off = 32; off; off >>= 1) mx = fmaxf(mx, __shfl_xor(mx, off));
    if ((threadIdx.x & 63) == 0) sh[threadIdx.x >> 6] = mx;
    __syncthreads();
    mx = fmaxf(sh[0], sh[1]);
    float e = __expf(v - mx);
    float ssum = e;
#pragma unroll
    for (int off = 32; off; off >>= 1) ssum += __shfl_xor(ssum, off);
    if ((threadIdx.x & 63) == 0) sh[2 + (threadIdx.x >> 6)] = ssum;
    __syncthreads();
    float out = e / (sh[2] + sh[3]);
    if (back) PbT[j * SS + i] = out;
    else      PfT[j * SS + i] = out;
}

// ---------------------------------------------------------------------------
// Convert w1 (512x64) and w2 (128x512) fp32 -> bf16
// ---------------------------------------------------------------------------
__global__ void conv_w(const float* __restrict__ w1, const float* __restrict__ w2,
                       ushort* __restrict__ w1b, ushort* __restrict__ w2b) {
    int i = blockIdx.x * 256 + threadIdx.x;
    const int N1 = HH * DD;
    const int N2 = SS * HH;
    if (i < N1) w1b[i] = f2bfu(w1[i]);
    else if (i < N1 + N2) w2b[i - N1] = f2bfu(w2[i - N1]);
}

// ---------------------------------------------------------------------------
// Fused MLP: emit[b][t][s] (bf16) = relu(obs@W1^T + b1) @ W2^T + b2
// ---------------------------------------------------------------------------
#define MLP_ROWS 32
__global__ __launch_bounds__(256) void mlp_kernel(
    const float* __restrict__ obs, const ushort* __restrict__ w1b,
    const ushort* __restrict__ w2b, const float* __restrict__ b1,
    const float* __restrict__ b2, ushort* __restrict__ emitb) {
    __shared__ __align__(16) ushort Alds[MLP_ROWS][72];
    __shared__ __align__(16) ushort Hlds[MLP_ROWS][520];

    int wg = blockIdx.x;
    int bb = wg >> 7;
    int t0 = (wg & 127) * MLP_ROWS;
    int tid = threadIdx.x;
    int lane = tid & 63, wv = tid >> 6;
    int lhi = lane >> 4, llo = lane & 15;

    {
        int r = tid >> 3, c0 = (tid & 7) * 8;
        const float* src = obs + ((size_t)bb * TT + t0 + r) * DD + c0;
        float4 v0 = *(const float4*)(src);
        float4 v1 = *(const float4*)(src + 4);
        Alds[r][c0 + 0] = f2bfu(v0.x); Alds[r][c0 + 1] = f2bfu(v0.y);
        Alds[r][c0 + 2] = f2bfu(v0.z); Alds[r][c0 + 3] = f2bfu(v0.w);
        Alds[r][c0 + 4] = f2bfu(v1.x); Alds[r][c0 + 5] = f2bfu(v1.y);
        Alds[r][c0 + 6] = f2bfu(v1.z); Alds[r][c0 + 7] = f2bfu(v1.w);
    }
    __syncthreads();

    f32x4 acc1[2][8];
#pragma unroll
    for (int mi = 0; mi < 2; ++mi)
#pragma unroll
        for (int ni = 0; ni < 8; ++ni) acc1[mi][ni] = (f32x4){0.f, 0.f, 0.f, 0.f};
    int nw0 = wv * 128;
#pragma unroll
    for (int kt = 0; kt < 2; ++kt) {
        s16x8 af[2];
#pragma unroll
        for (int mi = 0; mi < 2; ++mi)
            af[mi] = *(const s16x8*)(&Alds[mi * 16 + llo][kt * 32 + lhi * 8]);
#pragma unroll
        for (int ni = 0; ni < 8; ++ni) {
            int n = nw0 + ni * 16 + llo;
            s16x8 bf = *(const s16x8*)(w1b + n * DD + kt * 32 + lhi * 8);
#pragma unroll
            for (int mi = 0; mi < 2; ++mi)
                acc1[mi][ni] = __builtin_amdgcn_mfma_f32_16x16x32_bf16(af[mi], bf, acc1[mi][ni], 0, 0, 0);
        }
    }
#pragma unroll
    for (int ni = 0; ni < 8; ++ni) {
        int n = nw0 + ni * 16 + llo;
        float b1v = b1[n];
#pragma unroll
        for (int mi = 0; mi < 2; ++mi) {
#pragma unroll
            for (int r = 0; r < 4; ++r) {
                float hv = fmaxf(acc1[mi][ni][r] + b1v, 0.f);
                Hlds[mi * 16 + lhi * 4 + r][n] = f2bfu(hv);
            }
        }
    }
    __syncthreads();

    f32x4 acc2[2][2];
#pragma unroll
    for (int si = 0; si < 2; ++si)
#pragma unroll
        for (int nt = 0; nt < 2; ++nt) acc2[si][nt] = (f32x4){0.f, 0.f, 0.f, 0.f};
    int s0 = wv * 32;
#pragma unroll
    for (int kt = 0; kt < 16; ++kt) {
        s16x8 hf[2];
#pragma unroll
        for (int nt = 0; nt < 2; ++nt)
            hf[nt] = *(const s16x8*)(&Hlds[nt * 16 + llo][kt * 32 + lhi * 8]);
#pragma unroll
        for (int si = 0; si < 2; ++si) {
            int srow = s0 + si * 16 + llo;
            s16x8 wf = *(const s16x8*)(w2b + srow * HH + kt * 32 + lhi * 8);
#pragma unroll
            for (int nt = 0; nt < 2; ++nt)
                acc2[si][nt] = __builtin_amdgcn_mfma_f32_16x16x32_bf16(wf, hf[nt], acc2[si][nt], 0, 0, 0);
        }
    }
#pragma unroll
    for (int si = 0; si < 2; ++si) {
        int sbase = s0 + si * 16 + lhi * 4;
        float4 b2v = *(const float4*)(b2 + sbase);
#pragma unroll
        for (int nt = 0; nt < 2; ++nt) {
            int tl = nt * 16 + llo;
            ushort* dst = emitb + ((size_t)bb * TT + t0 + tl) * SS + sbase;
            s16x4 pk;
            pk[0] = (short)f2bfu(acc2[si][nt][0] + b2v.x);
            pk[1] = (short)f2bfu(acc2[si][nt][1] + b2v.y);
            pk[2] = (short)f2bfu(acc2[si][nt][2] + b2v.z);
            pk[3] = (short)f2bfu(acc2[si][nt][3] + b2v.w);
            *(s16x4*)dst = pk;
        }
    }
}

// ---------------------------------------------------------------------------
// Chunked scans. One WG = 256 threads = one (b, dir, chunk).
// State s = 32*wave + (lane>>1); half h = lane&1; each thread holds half of
// P^T column s pinned in VGPRs via asm identity (defeats rematerialization).
// pbuf upper half padded +4 dwords so the two broadcast groups hit disjoint
// banks. Raw s_barrier with lgkmcnt-only wait: no vmcnt(0) drain per step, so
// emit prefetch and alpha stores stay in flight across the barrier.
// ---------------------------------------------------------------------------
__global__ __launch_bounds__(256, 4) void scan_kernel(
    const ushort* __restrict__ emitb, const float* __restrict__ PfT,
    const float* __restrict__ PbT, float* __restrict__ galpha,
    float* __restrict__ gbeta) {
    int wg = blockIdx.x;            // 32 b * 2 dir * 16 chunks = 1024
    int c = wg & (NCHUNK - 1);
    int dir = (wg >> 4) & 1;
    int bb = wg >> 5;
    int tid = threadIdx.x;
    int w = tid >> 6, l = tid & 63;
    int s = w * 32 + (l >> 1);
    int h = l & 1;

    const float* PT = dir ? PbT : PfT;
    f32x4 pc[16];
#pragma unroll
    for (int i = 0; i < 16; ++i) pc[i] = *(const f32x4*)(PT + s * SS + h * 64 + i * 4);
    // opaque identity: compiler cannot rematerialize these loads inside the loop
#pragma unroll
    for (int i = 0; i < 16; ++i) asm volatile("" : "+v"(pc[i]));

    // upper half starts at dword 68 -> banks 4..7 vs 0..3: conflict-free
    __shared__ __align__(16) float pbuf[2][SS + 4];
    __shared__ float mslot[2];

    int warm = (dir == 0) ? (c > 0 ? CH_W : 0) : (c < NCHUNK - 1 ? CH_W : 0);
    int nstep = CH_L + warm;
    int tfirst = (dir == 0) ? c * CH_L - warm : c * CH_L + CH_L - 1 + warm;
    intptr_t estep = (dir == 0) ? (intptr_t)SS : -(intptr_t)SS;

    const ushort* erow = emitb + ((size_t)bb * TT + tfirst) * SS + s;
    float* outp = ((dir == 0) ? galpha : gbeta) + ((size_t)bb * TT + tfirst) * SS + s;

    float alpha = 0.f, m = 0.f;
    float ecur = bfu2f(erow[0]);
    float enext = bfu2f(erow[estep]);

    int widx = s + ((s >> 6) << 2);   // s<64 -> s ; s>=64 -> s+4
    int rbase = h * 68;

    for (int v = 0; v < nstep; ++v) {
        float p = __expf(fminf(alpha - m, 60.f));
        if (!h) pbuf[v & 1][widx] = p;
        if (tid == 0) mslot[v & 1] = alpha;
        // LDS-only barrier: drain lgkm (ds_writes), NOT vmcnt
        __builtin_amdgcn_sched_barrier(0);
        asm volatile("s_waitcnt lgkmcnt(0)" ::: "memory");
        __builtin_amdgcn_s_barrier();
        __builtin_amdgcn_sched_barrier(0);
        float mnext = mslot[v & 1];                       // alpha_{v-1}[0]
        ushort e2 = erow[(intptr_t)(v + 2) * estep];      // prefetch 2 ahead
        const float* pb = &pbuf[v & 1][rbase];
        float q0 = 0.f, q1 = 0.f, q2 = 0.f, q3 = 0.f;
#pragma unroll
        for (int i = 0; i < 16; ++i) {
            f32x4 pp = *(const f32x4*)(pb + i * 4);
            q0 = fmaf(pp.x, pc[i].x, q0);
            q1 = fmaf(pp.y, pc[i].y, q1);
            q2 = fmaf(pp.z, pc[i].z, q2);
            q3 = fmaf(pp.w, pc[i].w, q3);
        }
        float qt = (q0 + q1) + (q2 + q3);
        qt += __shfl_xor(qt, 1);
        alpha = m + __logf(qt) + ecur;
        if (v >= warm && !h) outp[(intptr_t)v * estep] = alpha;
        m = mnext;
        ecur = enext;
        enext = bfu2f(e2);
    }
}

// ---------------------------------------------------------------------------
// Combine: out[b][t][s] = softmax_s(alpha + beta)
// ---------------------------------------------------------------------------
__global__ __launch_bounds__(256) void combine_kernel(
    const float* __restrict__ galpha, const float* __restrict__ gbeta,
    float* __restrict__ out) {
    int row = blockIdx.x * 4 + (threadIdx.x >> 6);
    int lane = threadIdx.x & 63;
    size_t base = (size_t)row * SS + lane * 2;
    float2 a = *(const float2*)(galpha + base);
    float2 b = *(const float2*)(gbeta + base);
    float g0 = a.x + b.x, g1 = a.y + b.y;
    float mx = fmaxf(g0, g1);
#pragma unroll
    for (int off = 32; off; off >>= 1) mx = fmaxf(mx, __shfl_xor(mx, off));
    float e0 = __expf(g0 - mx), e1 = __expf(g1 - mx);
    float ssum = e0 + e1;
#pragma unroll
    for (int off = 32; off; off >>= 1) ssum += __shfl_xor(ssum, off);
    float inv = 1.f / ssum;
    float2 o; o.x = e0 * inv; o.y = e1 * inv;
    *(float2*)(out + base) = o;
}

// ---------------------------------------------------------------------------
extern "C" void kernel_launch(void* const* d_in, const int* in_sizes, int n_in,
                              void* d_out, int out_size, void* d_ws, size_t ws_size,
                              hipStream_t stream) {
    const float* obs = (const float*)d_in[0];
    const float* trans = (const float*)d_in[1];
    const float* w1 = (const float*)d_in[2];
    const float* b1 = (const float*)d_in[3];
    const float* w2 = (const float*)d_in[4];
    const float* b2 = (const float*)d_in[5];

    char* ws = (char*)d_ws;
    float* PfT = (float*)(ws);                         // 64 KB
    float* PbT = (float*)(ws + 65536);                 // 64 KB
    ushort* w1b = (ushort*)(ws + 131072);              // 64 KB
    ushort* w2b = (ushort*)(ws + 196608);              // 128 KB
    ushort* emitb = (ushort*)(ws + 327680);            // 32 MB
    float* galpha = (float*)(ws + 327680 + 33554432);  // 64 MB
    float* gbeta = (float*)(ws + 327680 + 33554432 + 67108864);  // 64 MB

    prep_trans<<<256, 128, 0, stream>>>(trans, PfT, PbT);
    conv_w<<<384, 256, 0, stream>>>(w1, w2, w1b, w2b);
    mlp_kernel<<<BB * (TT / MLP_ROWS), 256, 0, stream>>>(obs, w1b, w2b, b1, b2, emitb);
    scan_kernel<<<BB * 2 * NCHUNK, 256, 0, stream>>>(emitb, PfT, PbT, galpha, gbeta);
    combine_kernel<<<(BB * TT) / 4, 256, 0, stream>>>(galpha, gbeta, (float*)d_out);
}

// Round 4
// 240.942 us; speedup vs baseline: 2.0190x; 1.6273x over previous
//
#include <hip/hip_runtime.h>
#include <hip/hip_bf16.h>
#include <stdint.h>

#define BB 32
#define TT 4096
#define DD 64
#define SS 128
#define HH 512

#define SC_W 64
#define SC_L 64
// 64 chunks per (b,dir); 16 chains per WG; WGs = 32*2*4 = 256

typedef __attribute__((ext_vector_type(4))) float f32x4;
typedef __attribute__((ext_vector_type(8))) short s16x8;
typedef __attribute__((ext_vector_type(4))) short s16x4;

__device__ __forceinline__ ushort f2bfu(float x) {
    uint32_t b = __float_as_uint(x);
    uint32_t r = (b + 0x7FFFu + ((b >> 16) & 1u)) >> 16;
    return (ushort)r;
}
__device__ __forceinline__ float bfu2f(ushort u) {
    return __uint_as_float(((uint32_t)u) << 16);
}

// ---------------------------------------------------------------------------
// Prep: PfT[k][i] = softmax_row_i(trans)[k]; PbT[s][i] = softmax_col_i(trans)[s]
// ---------------------------------------------------------------------------
__global__ __launch_bounds__(128) void prep_trans(const float* __restrict__ tr,
                                                  float* __restrict__ PfT,
                                                  float* __restrict__ PbT) {
    int i = blockIdx.x & 127;
    int back = blockIdx.x >> 7;
    int j = threadIdx.x;
    float v = back ? tr[j * SS + i] : tr[i * SS + j];
    __shared__ float sh[4];
    float mx = v;
#pragma unroll
    for (int off = 32; off; off >>= 1) mx = fmaxf(mx, __shfl_xor(mx, off));
    if ((threadIdx.x & 63) == 0) sh[threadIdx.x >> 6] = mx;
    __syncthreads();
    mx = fmaxf(sh[0], sh[1]);
    float e = __expf(v - mx);
    float ssum = e;
#pragma unroll
    for (int off = 32; off; off >>= 1) ssum += __shfl_xor(ssum, off);
    if ((threadIdx.x & 63) == 0) sh[2 + (threadIdx.x >> 6)] = ssum;
    __syncthreads();
    float out = e / (sh[2] + sh[3]);
    if (back) PbT[j * SS + i] = out;
    else      PfT[j * SS + i] = out;
}

// ---------------------------------------------------------------------------
// Convert w1 (512x64) and w2 (128x512) fp32 -> bf16
// ---------------------------------------------------------------------------
__global__ void conv_w(const float* __restrict__ w1, const float* __restrict__ w2,
                       ushort* __restrict__ w1b, ushort* __restrict__ w2b) {
    int i = blockIdx.x * 256 + threadIdx.x;
    const int N1 = HH * DD;
    const int N2 = SS * HH;
    if (i < N1) w1b[i] = f2bfu(w1[i]);
    else if (i < N1 + N2) w2b[i - N1] = f2bfu(w2[i - N1]);
}

// ---------------------------------------------------------------------------
// Fused MLP: E[b][t][s] (bf16) = exp( relu(obs@W1^T + b1) @ W2^T + b2 )
// (stores the LINEAR-space emission likelihood for the linear scan)
// ---------------------------------------------------------------------------
#define MLP_ROWS 32
__global__ __launch_bounds__(256) void mlp_kernel(
    const float* __restrict__ obs, const ushort* __restrict__ w1b,
    const ushort* __restrict__ w2b, const float* __restrict__ b1,
    const float* __restrict__ b2, ushort* __restrict__ emitb) {
    __shared__ __align__(16) ushort Alds[MLP_ROWS][72];
    __shared__ __align__(16) ushort Hlds[MLP_ROWS][520];

    int wg = blockIdx.x;
    int bb = wg >> 7;
    int t0 = (wg & 127) * MLP_ROWS;
    int tid = threadIdx.x;
    int lane = tid & 63, wv = tid >> 6;
    int lhi = lane >> 4, llo = lane & 15;

    {
        int r = tid >> 3, c0 = (tid & 7) * 8;
        const float* src = obs + ((size_t)bb * TT + t0 + r) * DD + c0;
        float4 v0 = *(const float4*)(src);
        float4 v1 = *(const float4*)(src + 4);
        Alds[r][c0 + 0] = f2bfu(v0.x); Alds[r][c0 + 1] = f2bfu(v0.y);
        Alds[r][c0 + 2] = f2bfu(v0.z); Alds[r][c0 + 3] = f2bfu(v0.w);
        Alds[r][c0 + 4] = f2bfu(v1.x); Alds[r][c0 + 5] = f2bfu(v1.y);
        Alds[r][c0 + 6] = f2bfu(v1.z); Alds[r][c0 + 7] = f2bfu(v1.w);
    }
    __syncthreads();

    f32x4 acc1[2][8];
#pragma unroll
    for (int mi = 0; mi < 2; ++mi)
#pragma unroll
        for (int ni = 0; ni < 8; ++ni) acc1[mi][ni] = (f32x4){0.f, 0.f, 0.f, 0.f};
    int nw0 = wv * 128;
#pragma unroll
    for (int kt = 0; kt < 2; ++kt) {
        s16x8 af[2];
#pragma unroll
        for (int mi = 0; mi < 2; ++mi)
            af[mi] = *(const s16x8*)(&Alds[mi * 16 + llo][kt * 32 + lhi * 8]);
#pragma unroll
        for (int ni = 0; ni < 8; ++ni) {
            int n = nw0 + ni * 16 + llo;
            s16x8 bf = *(const s16x8*)(w1b + n * DD + kt * 32 + lhi * 8);
#pragma unroll
            for (int mi = 0; mi < 2; ++mi)
                acc1[mi][ni] = __builtin_amdgcn_mfma_f32_16x16x32_bf16(af[mi], bf, acc1[mi][ni], 0, 0, 0);
        }
    }
#pragma unroll
    for (int ni = 0; ni < 8; ++ni) {
        int n = nw0 + ni * 16 + llo;
        float b1v = b1[n];
#pragma unroll
        for (int mi = 0; mi < 2; ++mi) {
#pragma unroll
            for (int r = 0; r < 4; ++r) {
                float hv = fmaxf(acc1[mi][ni][r] + b1v, 0.f);
                Hlds[mi * 16 + lhi * 4 + r][n] = f2bfu(hv);
            }
        }
    }
    __syncthreads();

    f32x4 acc2[2][2];
#pragma unroll
    for (int si = 0; si < 2; ++si)
#pragma unroll
        for (int nt = 0; nt < 2; ++nt) acc2[si][nt] = (f32x4){0.f, 0.f, 0.f, 0.f};
    int s0 = wv * 32;
#pragma unroll
    for (int kt = 0; kt < 16; ++kt) {
        s16x8 hf[2];
#pragma unroll
        for (int nt = 0; nt < 2; ++nt)
            hf[nt] = *(const s16x8*)(&Hlds[nt * 16 + llo][kt * 32 + lhi * 8]);
#pragma unroll
        for (int si = 0; si < 2; ++si) {
            int srow = s0 + si * 16 + llo;
            s16x8 wf = *(const s16x8*)(w2b + srow * HH + kt * 32 + lhi * 8);
#pragma unroll
            for (int nt = 0; nt < 2; ++nt)
                acc2[si][nt] = __builtin_amdgcn_mfma_f32_16x16x32_bf16(wf, hf[nt], acc2[si][nt], 0, 0, 0);
        }
    }
#pragma unroll
    for (int si = 0; si < 2; ++si) {
        int sbase = s0 + si * 16 + lhi * 4;
        float4 b2v = *(const float4*)(b2 + sbase);
#pragma unroll
        for (int nt = 0; nt < 2; ++nt) {
            int tl = nt * 16 + llo;
            ushort* dst = emitb + ((size_t)bb * TT + t0 + tl) * SS + sbase;
            s16x4 pk;
            pk[0] = (short)f2bfu(__expf(acc2[si][nt][0] + b2v.x));
            pk[1] = (short)f2bfu(__expf(acc2[si][nt][1] + b2v.y));
            pk[2] = (short)f2bfu(__expf(acc2[si][nt][2] + b2v.z));
            pk[3] = (short)f2bfu(__expf(acc2[si][nt][3] + b2v.w));
            *(s16x4*)dst = pk;
        }
    }
}

// ---------------------------------------------------------------------------
// MFMA-batched linear-space scan. One WG (256 thr, 4 waves) = 16 chains
// (16 consecutive chunks of one (b,dir)). Per step: p(16x128) @ P(128x128)
// via mfma_f32_16x16x32_bf16, P static in VGPRs as bf16 hi+lo (error ~2^-16),
// p relayout C-frag -> A-frag via double-buffered LDS, ONE raw barrier/step
// (lgkmcnt only -- E prefetch + pa stores stay in flight). Rescale: lag-1
// r = rcp(p[chain][0]) broadcast via LDS. Warm chunks: 64 junk steps (clamped
// t), boundary chains reset to uniform at v=63. Posteriors normalize away
// all per-(t,chain) scales, so no exp/log anywhere in the loop.
// ---------------------------------------------------------------------------
__global__ __launch_bounds__(256, 1) void scan_mfma(
    const ushort* __restrict__ Eb, const float* __restrict__ PfT,
    const float* __restrict__ PbT, float* __restrict__ galpha,
    float* __restrict__ gbeta) {
    int wg = blockIdx.x;            // 32 b * 2 dir * 4 = 256
    int b = wg >> 3;
    int dir = (wg >> 2) & 1;
    int wgc = wg & 3;               // 16-chunk group
    int resetRow = (dir == 0) ? (wgc == 0 ? 0 : -1) : (wgc == 3 ? 15 : -1);
    int tid = threadIdx.x;
    int l = tid & 63, w = tid >> 6;
    int l15 = l & 15, g = l >> 4;
    int d = dir ? -1 : 1;

    const float* PT = dir ? PbT : PfT;
    float* paB = (dir ? gbeta : galpha) + (size_t)b * TT * SS;
    const ushort* EbB = Eb + (size_t)b * TT * SS;

    int col0 = w * 32 + l15;
    int col1 = col0 + 16;

    // ---- static B fragments: PT[s][k] split into bf16 hi + lo ----
    s16x8 Bhi[2][4], Blo[2][4];
#pragma unroll
    for (int tile = 0; tile < 2; ++tile) {
        int srow = w * 32 + tile * 16 + l15;
#pragma unroll
        for (int kt = 0; kt < 4; ++kt) {
            const float* src = PT + srow * SS + kt * 32 + g * 8;
            float x[8];
            *(float4*)(x) = *(const float4*)(src);
            *(float4*)(x + 4) = *(const float4*)(src + 4);
            s16x8 hi, lo;
#pragma unroll
            for (int j = 0; j < 8; ++j) {
                uint32_t bx = __float_as_uint(x[j]);
                uint32_t hb = bx & 0xFFFF0000u;
                float rem = x[j] - __uint_as_float(hb);   // exact
                hi[j] = (short)(hb >> 16);
                lo[j] = (short)f2bfu(rem);
            }
            Bhi[tile][kt] = hi; Blo[tile][kt] = lo;
        }
    }
    // pin: forbid rematerialization of the P fragments inside the loop
#pragma unroll
    for (int tile = 0; tile < 2; ++tile)
#pragma unroll
        for (int kt = 0; kt < 4; ++kt) {
            asm volatile("" : "+v"(Bhi[tile][kt]));
            asm volatile("" : "+v"(Blo[tile][kt]));
        }

    __shared__ __align__(16) ushort Ahi[2][16][136];   // stride 272B: 16B-aligned
    __shared__ __align__(16) ushort Alo[2][16][136];
    __shared__ __align__(16) float mscale[2][16];

    // init: p = 1 uniform (bf16 1.0 = 0x3F80), scale r = 1
    for (int i = tid; i < 16 * 136; i += 256) {
        (&Ahi[0][0][0])[i] = (ushort)0x3F80;
        (&Alo[0][0][0])[i] = (ushort)0;
    }
    if (tid < 16) mscale[0][tid] = 1.0f;

    // per-row time counters (row = 4g+j -> chain = wgc*16 + 4g + j)
    int tj[4];
#pragma unroll
    for (int j = 0; j < 4; ++j) {
        int chain = wgc * 16 + 4 * g + j;
        tj[j] = dir ? chain * SC_L + (SC_L - 1) + SC_W : chain * SC_L - SC_W;
    }

    __syncthreads();

    // preload E for v=0
    ushort EA[8], EB[8];
#pragma unroll
    for (int j = 0; j < 4; ++j) {
        int tc = tj[j] < 0 ? 0 : (tj[j] > TT - 1 ? TT - 1 : tj[j]);
        uint32_t ro = (uint32_t)tc << 7;
        EA[j] = EbB[ro + col0];
        EA[4 + j] = EbB[ro + col1];
    }

#define SCAN_STEP(v, par, EC, EN, DOSTORE, DORESET)                              \
    do {                                                                         \
        _Pragma("unroll") for (int j = 0; j < 4; ++j) {    /* E prefetch v+1 */  \
            int tn = tj[j] + d;                                                  \
            int tc = tn < 0 ? 0 : (tn > TT - 1 ? TT - 1 : tn);                   \
            uint32_t ro = (uint32_t)tc << 7;                                     \
            EN[j] = EbB[ro + col0];                                              \
            EN[4 + j] = EbB[ro + col1];                                          \
        }                                                                        \
        s16x8 ahi[4], alo[4];                                                    \
        _Pragma("unroll") for (int kt = 0; kt < 4; ++kt) {                       \
            ahi[kt] = *(const s16x8*)(&Ahi[par][l15][kt * 32 + g * 8]);          \
            alo[kt] = *(const s16x8*)(&Alo[par][l15][kt * 32 + g * 8]);          \
        }                                                                        \
        f32x4 rs = *(const f32x4*)(&mscale[par][4 * g]);                         \
        f32x4 aHH0 = {0,0,0,0}, aHL0 = {0,0,0,0}, aLH0 = {0,0,0,0};              \
        f32x4 aHH1 = {0,0,0,0}, aHL1 = {0,0,0,0}, aLH1 = {0,0,0,0};              \
        _Pragma("unroll") for (int kt = 0; kt < 4; ++kt) {                       \
            aHH0 = __builtin_amdgcn_mfma_f32_16x16x32_bf16(ahi[kt], Bhi[0][kt], aHH0, 0, 0, 0); \
            aHH1 = __builtin_amdgcn_mfma_f32_16x16x32_bf16(ahi[kt], Bhi[1][kt], aHH1, 0, 0, 0); \
            aHL0 = __builtin_amdgcn_mfma_f32_16x16x32_bf16(ahi[kt], Blo[0][kt], aHL0, 0, 0, 0); \
            aHL1 = __builtin_amdgcn_mfma_f32_16x16x32_bf16(ahi[kt], Blo[1][kt], aHL1, 0, 0, 0); \
            aLH0 = __builtin_amdgcn_mfma_f32_16x16x32_bf16(alo[kt], Bhi[0][kt], aLH0, 0, 0, 0); \
            aLH1 = __builtin_amdgcn_mfma_f32_16x16x32_bf16(alo[kt], Bhi[1][kt], aLH1, 0, 0, 0); \
        }                                                                        \
        f32x4 acc0 = (aHH0 + aHL0) + aLH0;                                       \
        f32x4 acc1 = (aHH1 + aHL1) + aLH1;                                       \
        float pv[8];                                                             \
        _Pragma("unroll") for (int j = 0; j < 4; ++j) {                          \
            pv[j] = acc0[j] * (bfu2f(EC[j]) * rs[j]);                            \
            pv[4 + j] = acc1[j] * (bfu2f(EC[4 + j]) * rs[j]);                    \
            if (DORESET && (v) == SC_W - 1 && resetRow == 4 * g + j) {           \
                pv[j] = 1.f; pv[4 + j] = 1.f;                                    \
            }                                                                    \
            if (DOSTORE) {                                                       \
                uint32_t po = (uint32_t)tj[j] << 7;                              \
                paB[po + col0] = pv[j];                                          \
                paB[po + col1] = pv[4 + j];                                      \
            }                                                                    \
            tj[j] += d;                                                          \
        }                                                                        \
        _Pragma("unroll") for (int j = 0; j < 4; ++j) {   /* write A(v+1) */     \
            int rr = 4 * g + j;                                                  \
            uint32_t b0 = __float_as_uint(pv[j]);                                \
            uint32_t h0 = b0 & 0xFFFF0000u;                                      \
            float r0 = pv[j] - __uint_as_float(h0);                              \
            Ahi[(par) ^ 1][rr][col0] = (ushort)(h0 >> 16);                       \
            Alo[(par) ^ 1][rr][col0] = f2bfu(r0);                                \
            uint32_t b1 = __float_as_uint(pv[4 + j]);                            \
            uint32_t h1 = b1 & 0xFFFF0000u;                                      \
            float r1 = pv[4 + j] - __uint_as_float(h1);                          \
            Ahi[(par) ^ 1][rr][col1] = (ushort)(h1 >> 16);                       \
            Alo[(par) ^ 1][rr][col1] = f2bfu(r1);                                \
        }                                                                        \
        if (w == 0 && l15 == 0) {                        /* scale writers */     \
            f32x4 rn;                                                            \
            _Pragma("unroll") for (int j = 0; j < 4; ++j)                        \
                rn[j] = __builtin_amdgcn_rcpf(pv[j]);                            \
            *(f32x4*)(&mscale[(par) ^ 1][4 * g]) = rn;                           \
        }                                                                        \
        __builtin_amdgcn_sched_barrier(0);                                       \
        asm volatile("s_waitcnt lgkmcnt(0)" ::: "memory");                       \
        __builtin_amdgcn_s_barrier();                                            \
        __builtin_amdgcn_sched_barrier(0);                                       \
    } while (0)

    // warm phase: v = 0..63 (no stores; boundary chains reset at v=63)
    for (int v2 = 0; v2 < SC_W / 2; ++v2) {
        SCAN_STEP(2 * v2, 0, EA, EB, false, true);
        SCAN_STEP(2 * v2 + 1, 1, EB, EA, false, true);
    }
    // main phase: v = 64..127 (stores, no reset)
    for (int v2 = 0; v2 < SC_L / 2; ++v2) {
        SCAN_STEP(SC_W + 2 * v2, 0, EA, EB, true, false);
        SCAN_STEP(SC_W + 2 * v2 + 1, 1, EB, EA, true, false);
    }
#undef SCAN_STEP
}

// ---------------------------------------------------------------------------
// Combine (linear): out[b][t][s] = pa*pb / sum_s(pa*pb)   (scales cancel)
// ---------------------------------------------------------------------------
__global__ __launch_bounds__(256) void combine_kernel(
    const float* __restrict__ galpha, const float* __restrict__ gbeta,
    float* __restrict__ out) {
    int row = blockIdx.x * 4 + (threadIdx.x >> 6);
    int lane = threadIdx.x & 63;
    size_t base = (size_t)row * SS + lane * 2;
    float2 a = *(const float2*)(galpha + base);
    float2 b = *(const float2*)(gbeta + base);
    float g0 = a.x * b.x, g1 = a.y * b.y;
    float ssum = g0 + g1;
#pragma unroll
    for (int off = 32; off; off >>= 1) ssum += __shfl_xor(ssum, off);
    float inv = 1.f / ssum;
    float2 o; o.x = g0 * inv; o.y = g1 * inv;
    *(float2*)(out + base) = o;
}

// ---------------------------------------------------------------------------
extern "C" void kernel_launch(void* const* d_in, const int* in_sizes, int n_in,
                              void* d_out, int out_size, void* d_ws, size_t ws_size,
                              hipStream_t stream) {
    const float* obs = (const float*)d_in[0];
    const float* trans = (const float*)d_in[1];
    const float* w1 = (const float*)d_in[2];
    const float* b1 = (const float*)d_in[3];
    const float* w2 = (const float*)d_in[4];
    const float* b2 = (const float*)d_in[5];

    char* ws = (char*)d_ws;
    float* PfT = (float*)(ws);                         // 64 KB
    float* PbT = (float*)(ws + 65536);                 // 64 KB
    ushort* w1b = (ushort*)(ws + 131072);              // 64 KB
    ushort* w2b = (ushort*)(ws + 196608);              // 128 KB
    ushort* emitb = (ushort*)(ws + 327680);            // 32 MB (E = exp(emit), bf16)
    float* galpha = (float*)(ws + 327680 + 33554432);  // 64 MB
    float* gbeta = (float*)(ws + 327680 + 33554432 + 67108864);  // 64 MB

    prep_trans<<<256, 128, 0, stream>>>(trans, PfT, PbT);
    conv_w<<<384, 256, 0, stream>>>(w1, w2, w1b, w2b);
    mlp_kernel<<<BB * (TT / MLP_ROWS), 256, 0, stream>>>(obs, w1b, w2b, b1, b2, emitb);
    scan_mfma<<<256, 256, 0, stream>>>(emitb, PfT, PbT, galpha, gbeta);
    combine_kernel<<<(BB * TT) / 4, 256, 0, stream>>>(galpha, gbeta, (float*)d_out);
}

// Round 5
// 211.533 us; speedup vs baseline: 2.2997x; 1.1390x over previous
//
#include <hip/hip_runtime.h>
#include <hip/hip_bf16.h>
#include <stdint.h>

#define BB 32
#define TT 4096
#define DD 64
#define SS 128
#define HH 512

#define SC_W 64
#define SC_L 64

typedef __attribute__((ext_vector_type(4))) float f32x4;
typedef __attribute__((ext_vector_type(8))) short s16x8;
typedef __attribute__((ext_vector_type(4))) short s16x4;

__device__ __forceinline__ ushort f2bfu(float x) {
    uint32_t b = __float_as_uint(x);
    uint32_t r = (b + 0x7FFFu + ((b >> 16) & 1u)) >> 16;
    return (ushort)r;
}
__device__ __forceinline__ float bfu2f(ushort u) {
    return __uint_as_float(((uint32_t)u) << 16);
}

// ---------------------------------------------------------------------------
// Prep: PfT[k][i] = softmax_row_i(trans)[k]; PbT[s][i] = softmax_col_i(trans)[s]
// ---------------------------------------------------------------------------
__global__ __launch_bounds__(128) void prep_trans(const float* __restrict__ tr,
                                                  float* __restrict__ PfT,
                                                  float* __restrict__ PbT) {
    int i = blockIdx.x & 127;
    int back = blockIdx.x >> 7;
    int j = threadIdx.x;
    float v = back ? tr[j * SS + i] : tr[i * SS + j];
    __shared__ float sh[4];
    float mx = v;
#pragma unroll
    for (int off = 32; off; off >>= 1) mx = fmaxf(mx, __shfl_xor(mx, off));
    if ((threadIdx.x & 63) == 0) sh[threadIdx.x >> 6] = mx;
    __syncthreads();
    mx = fmaxf(sh[0], sh[1]);
    float e = __expf(v - mx);
    float ssum = e;
#pragma unroll
    for (int off = 32; off; off >>= 1) ssum += __shfl_xor(ssum, off);
    if ((threadIdx.x & 63) == 0) sh[2 + (threadIdx.x >> 6)] = ssum;
    __syncthreads();
    float out = e / (sh[2] + sh[3]);
    if (back) PbT[j * SS + i] = out;
    else      PfT[j * SS + i] = out;
}

// ---------------------------------------------------------------------------
// Convert w1 (512x64) and w2 (128x512) fp32 -> bf16
// ---------------------------------------------------------------------------
__global__ void conv_w(const float* __restrict__ w1, const float* __restrict__ w2,
                       ushort* __restrict__ w1b, ushort* __restrict__ w2b) {
    int i = blockIdx.x * 256 + threadIdx.x;
    const int N1 = HH * DD;
    const int N2 = SS * HH;
    if (i < N1) w1b[i] = f2bfu(w1[i]);
    else if (i < N1 + N2) w2b[i - N1] = f2bfu(w2[i - N1]);
}

// ---------------------------------------------------------------------------
// Fused MLP: E[b][t][s] (bf16) = exp( relu(obs@W1^T + b1) @ W2^T + b2 )
// 64 t-rows per WG, 512 threads (8 waves). GEMM1: wave -> 64 h-cols.
// GEMM2 (transposed): wave -> 16 s-rows x 64 t. Hlds stride 524 ushort
// (262 dw = 6 mod 32) -> epilogue-1 row groups hit disjoint banks.
// ---------------------------------------------------------------------------
#define MLP_ROWS 64
__global__ __launch_bounds__(512, 2) void mlp_kernel(
    const float* __restrict__ obs, const ushort* __restrict__ w1b,
    const ushort* __restrict__ w2b, const float* __restrict__ b1,
    const float* __restrict__ b2, ushort* __restrict__ emitb) {
    __shared__ __align__(16) ushort Alds[MLP_ROWS][72];    // 9.2 KB
    __shared__ __align__(16) ushort Hlds[MLP_ROWS][524];   // 67.1 KB

    int wg = blockIdx.x;                  // 32 * 64 = 2048
    int bb = wg >> 6;
    int t0 = (wg & 63) * MLP_ROWS;
    int tid = threadIdx.x;
    int lane = tid & 63, wv = tid >> 6;   // wv 0..7
    int lhi = lane >> 4, llo = lane & 15;

    // stage obs tile -> bf16 LDS (64x64), one packed 16B store per thread
    {
        int r = tid >> 3, c0 = (tid & 7) * 8;
        const float* src = obs + ((size_t)bb * TT + t0 + r) * DD + c0;
        float4 v0 = *(const float4*)(src);
        float4 v1 = *(const float4*)(src + 4);
        s16x8 pk;
        pk[0] = (short)f2bfu(v0.x); pk[1] = (short)f2bfu(v0.y);
        pk[2] = (short)f2bfu(v0.z); pk[3] = (short)f2bfu(v0.w);
        pk[4] = (short)f2bfu(v1.x); pk[5] = (short)f2bfu(v1.y);
        pk[6] = (short)f2bfu(v1.z); pk[7] = (short)f2bfu(v1.w);
        *(s16x8*)(&Alds[r][c0]) = pk;
    }
    __syncthreads();

    // GEMM1: M=64(t) x N=64(h per wave) x K=64(d). acc1[mi][ni], 32 MFMAs.
    f32x4 acc1[4][4];
#pragma unroll
    for (int mi = 0; mi < 4; ++mi)
#pragma unroll
        for (int ni = 0; ni < 4; ++ni) acc1[mi][ni] = (f32x4){0.f, 0.f, 0.f, 0.f};
    int nw0 = wv * 64;
#pragma unroll
    for (int kt = 0; kt < 2; ++kt) {
        s16x8 af[4];
#pragma unroll
        for (int mi = 0; mi < 4; ++mi)
            af[mi] = *(const s16x8*)(&Alds[mi * 16 + llo][kt * 32 + lhi * 8]);
#pragma unroll
        for (int ni = 0; ni < 4; ++ni) {
            int n = nw0 + ni * 16 + llo;
            s16x8 bf = *(const s16x8*)(w1b + n * DD + kt * 32 + lhi * 8);
#pragma unroll
            for (int mi = 0; mi < 4; ++mi)
                acc1[mi][ni] = __builtin_amdgcn_mfma_f32_16x16x32_bf16(af[mi], bf, acc1[mi][ni], 0, 0, 0);
        }
    }
    // epilogue 1: +b1, relu -> Hlds[t][h] bf16
#pragma unroll
    for (int ni = 0; ni < 4; ++ni) {
        int n = nw0 + ni * 16 + llo;
        float b1v = b1[n];
#pragma unroll
        for (int mi = 0; mi < 4; ++mi) {
#pragma unroll
            for (int r = 0; r < 4; ++r) {
                float hv = fmaxf(acc1[mi][ni][r] + b1v, 0.f);
                Hlds[mi * 16 + lhi * 4 + r][n] = f2bfu(hv);
            }
        }
    }
    __syncthreads();

    // GEMM2 (transposed): eT[s][t] = W2 @ H^T. Wave wv: s in [wv*16, wv*16+16),
    // all 64 t. acc2[nt], 64 MFMAs; hf shared across the single s-tile.
    f32x4 acc2[4];
#pragma unroll
    for (int nt = 0; nt < 4; ++nt) acc2[nt] = (f32x4){0.f, 0.f, 0.f, 0.f};
    int s0 = wv * 16;
#pragma unroll
    for (int kt = 0; kt < 16; ++kt) {
        s16x8 wf = *(const s16x8*)(w2b + (s0 + llo) * HH + kt * 32 + lhi * 8);
#pragma unroll
        for (int nt = 0; nt < 4; ++nt) {
            s16x8 hf = *(const s16x8*)(&Hlds[nt * 16 + llo][kt * 32 + lhi * 8]);
            acc2[nt] = __builtin_amdgcn_mfma_f32_16x16x32_bf16(wf, hf, acc2[nt], 0, 0, 0);
        }
    }
    // epilogue 2: +b2, exp -> E[b][t][s] bf16 (4 consecutive s -> 8B store)
    {
        int sbase = s0 + lhi * 4;
        float4 b2v = *(const float4*)(b2 + sbase);
#pragma unroll
        for (int nt = 0; nt < 4; ++nt) {
            int tl = nt * 16 + llo;
            ushort* dst = emitb + ((size_t)bb * TT + t0 + tl) * SS + sbase;
            s16x4 pk;
            pk[0] = (short)f2bfu(__expf(acc2[nt][0] + b2v.x));
            pk[1] = (short)f2bfu(__expf(acc2[nt][1] + b2v.y));
            pk[2] = (short)f2bfu(__expf(acc2[nt][2] + b2v.z));
            pk[3] = (short)f2bfu(__expf(acc2[nt][3] + b2v.w));
            *(s16x4*)dst = pk;
        }
    }
}

// ---------------------------------------------------------------------------
// MFMA-batched linear-space scan (unchanged from round 4).
// ---------------------------------------------------------------------------
__global__ __launch_bounds__(256, 1) void scan_mfma(
    const ushort* __restrict__ Eb, const float* __restrict__ PfT,
    const float* __restrict__ PbT, float* __restrict__ galpha,
    float* __restrict__ gbeta) {
    int wg = blockIdx.x;            // 32 b * 2 dir * 4 = 256
    int b = wg >> 3;
    int dir = (wg >> 2) & 1;
    int wgc = wg & 3;
    int resetRow = (dir == 0) ? (wgc == 0 ? 0 : -1) : (wgc == 3 ? 15 : -1);
    int tid = threadIdx.x;
    int l = tid & 63, w = tid >> 6;
    int l15 = l & 15, g = l >> 4;
    int d = dir ? -1 : 1;

    const float* PT = dir ? PbT : PfT;
    float* paB = (dir ? gbeta : galpha) + (size_t)b * TT * SS;
    const ushort* EbB = Eb + (size_t)b * TT * SS;

    int col0 = w * 32 + l15;
    int col1 = col0 + 16;

    s16x8 Bhi[2][4], Blo[2][4];
#pragma unroll
    for (int tile = 0; tile < 2; ++tile) {
        int srow = w * 32 + tile * 16 + l15;
#pragma unroll
        for (int kt = 0; kt < 4; ++kt) {
            const float* src = PT + srow * SS + kt * 32 + g * 8;
            float x[8];
            *(float4*)(x) = *(const float4*)(src);
            *(float4*)(x + 4) = *(const float4*)(src + 4);
            s16x8 hi, lo;
#pragma unroll
            for (int j = 0; j < 8; ++j) {
                uint32_t bx = __float_as_uint(x[j]);
                uint32_t hb = bx & 0xFFFF0000u;
                float rem = x[j] - __uint_as_float(hb);
                hi[j] = (short)(hb >> 16);
                lo[j] = (short)f2bfu(rem);
            }
            Bhi[tile][kt] = hi; Blo[tile][kt] = lo;
        }
    }
#pragma unroll
    for (int tile = 0; tile < 2; ++tile)
#pragma unroll
        for (int kt = 0; kt < 4; ++kt) {
            asm volatile("" : "+v"(Bhi[tile][kt]));
            asm volatile("" : "+v"(Blo[tile][kt]));
        }

    __shared__ __align__(16) ushort Ahi[2][16][136];
    __shared__ __align__(16) ushort Alo[2][16][136];
    __shared__ __align__(16) float mscale[2][16];

    for (int i = tid; i < 16 * 136; i += 256) {
        (&Ahi[0][0][0])[i] = (ushort)0x3F80;
        (&Alo[0][0][0])[i] = (ushort)0;
    }
    if (tid < 16) mscale[0][tid] = 1.0f;

    int tj[4];
#pragma unroll
    for (int j = 0; j < 4; ++j) {
        int chain = wgc * 16 + 4 * g + j;
        tj[j] = dir ? chain * SC_L + (SC_L - 1) + SC_W : chain * SC_L - SC_W;
    }

    __syncthreads();

    ushort EA[8], EB[8];
#pragma unroll
    for (int j = 0; j < 4; ++j) {
        int tc = tj[j] < 0 ? 0 : (tj[j] > TT - 1 ? TT - 1 : tj[j]);
        uint32_t ro = (uint32_t)tc << 7;
        EA[j] = EbB[ro + col0];
        EA[4 + j] = EbB[ro + col1];
    }

#define SCAN_STEP(v, par, EC, EN, DOSTORE, DORESET)                              \
    do {                                                                         \
        _Pragma("unroll") for (int j = 0; j < 4; ++j) {                          \
            int tn = tj[j] + d;                                                  \
            int tc = tn < 0 ? 0 : (tn > TT - 1 ? TT - 1 : tn);                   \
            uint32_t ro = (uint32_t)tc << 7;                                     \
            EN[j] = EbB[ro + col0];                                              \
            EN[4 + j] = EbB[ro + col1];                                          \
        }                                                                        \
        s16x8 ahi[4], alo[4];                                                    \
        _Pragma("unroll") for (int kt = 0; kt < 4; ++kt) {                       \
            ahi[kt] = *(const s16x8*)(&Ahi[par][l15][kt * 32 + g * 8]);          \
            alo[kt] = *(const s16x8*)(&Alo[par][l15][kt * 32 + g * 8]);          \
        }                                                                        \
        f32x4 rs = *(const f32x4*)(&mscale[par][4 * g]);                         \
        f32x4 aHH0 = {0,0,0,0}, aHL0 = {0,0,0,0}, aLH0 = {0,0,0,0};              \
        f32x4 aHH1 = {0,0,0,0}, aHL1 = {0,0,0,0}, aLH1 = {0,0,0,0};              \
        _Pragma("unroll") for (int kt = 0; kt < 4; ++kt) {                       \
            aHH0 = __builtin_amdgcn_mfma_f32_16x16x32_bf16(ahi[kt], Bhi[0][kt], aHH0, 0, 0, 0); \
            aHH1 = __builtin_amdgcn_mfma_f32_16x16x32_bf16(ahi[kt], Bhi[1][kt], aHH1, 0, 0, 0); \
            aHL0 = __builtin_amdgcn_mfma_f32_16x16x32_bf16(ahi[kt], Blo[0][kt], aHL0, 0, 0, 0); \
            aHL1 = __builtin_amdgcn_mfma_f32_16x16x32_bf16(ahi[kt], Blo[1][kt], aHL1, 0, 0, 0); \
            aLH0 = __builtin_amdgcn_mfma_f32_16x16x32_bf16(alo[kt], Bhi[0][kt], aLH0, 0, 0, 0); \
            aLH1 = __builtin_amdgcn_mfma_f32_16x16x32_bf16(alo[kt], Bhi[1][kt], aLH1, 0, 0, 0); \
        }                                                                        \
        f32x4 acc0 = (aHH0 + aHL0) + aLH0;                                       \
        f32x4 acc1 = (aHH1 + aHL1) + aLH1;                                       \
        float pv[8];                                                             \
        _Pragma("unroll") for (int j = 0; j < 4; ++j) {                          \
            pv[j] = acc0[j] * (bfu2f(EC[j]) * rs[j]);                            \
            pv[4 + j] = acc1[j] * (bfu2f(EC[4 + j]) * rs[j]);                    \
            if (DORESET && (v) == SC_W - 1 && resetRow == 4 * g + j) {           \
                pv[j] = 1.f; pv[4 + j] = 1.f;                                    \
            }                                                                    \
            if (DOSTORE) {                                                       \
                uint32_t po = (uint32_t)tj[j] << 7;                              \
                paB[po + col0] = pv[j];                                          \
                paB[po + col1] = pv[4 + j];                                      \
            }                                                                    \
            tj[j] += d;                                                          \
        }                                                                        \
        _Pragma("unroll") for (int j = 0; j < 4; ++j) {                          \
            int rr = 4 * g + j;                                                  \
            uint32_t b0 = __float_as_uint(pv[j]);                                \
            uint32_t h0 = b0 & 0xFFFF0000u;                                      \
            float r0 = pv[j] - __uint_as_float(h0);                              \
            Ahi[(par) ^ 1][rr][col0] = (ushort)(h0 >> 16);                       \
            Alo[(par) ^ 1][rr][col0] = f2bfu(r0);                                \
            uint32_t b1 = __float_as_uint(pv[4 + j]);                            \
            uint32_t h1 = b1 & 0xFFFF0000u;                                      \
            float r1 = pv[4 + j] - __uint_as_float(h1);                          \
            Ahi[(par) ^ 1][rr][col1] = (ushort)(h1 >> 16);                       \
            Alo[(par) ^ 1][rr][col1] = f2bfu(r1);                                \
        }                                                                        \
        if (w == 0 && l15 == 0) {                                                \
            f32x4 rn;                                                            \
            _Pragma("unroll") for (int j = 0; j < 4; ++j)                        \
                rn[j] = __builtin_amdgcn_rcpf(pv[j]);                            \
            *(f32x4*)(&mscale[(par) ^ 1][4 * g]) = rn;                           \
        }                                                                        \
        __builtin_amdgcn_sched_barrier(0);                                       \
        asm volatile("s_waitcnt lgkmcnt(0)" ::: "memory");                       \
        __builtin_amdgcn_s_barrier();                                            \
        __builtin_amdgcn_sched_barrier(0);                                       \
    } while (0)

    for (int v2 = 0; v2 < SC_W / 2; ++v2) {
        SCAN_STEP(2 * v2, 0, EA, EB, false, true);
        SCAN_STEP(2 * v2 + 1, 1, EB, EA, false, true);
    }
    for (int v2 = 0; v2 < SC_L / 2; ++v2) {
        SCAN_STEP(SC_W + 2 * v2, 0, EA, EB, true, false);
        SCAN_STEP(SC_W + 2 * v2 + 1, 1, EB, EA, true, false);
    }
#undef SCAN_STEP
}

// ---------------------------------------------------------------------------
// Combine (linear): out[b][t][s] = pa*pb / sum_s(pa*pb)
// ---------------------------------------------------------------------------
__global__ __launch_bounds__(256) void combine_kernel(
    const float* __restrict__ galpha, const float* __restrict__ gbeta,
    float* __restrict__ out) {
    int row = blockIdx.x * 4 + (threadIdx.x >> 6);
    int lane = threadIdx.x & 63;
    size_t base = (size_t)row * SS + lane * 2;
    float2 a = *(const float2*)(galpha + base);
    float2 b = *(const float2*)(gbeta + base);
    float g0 = a.x * b.x, g1 = a.y * b.y;
    float ssum = g0 + g1;
#pragma unroll
    for (int off = 32; off; off >>= 1) ssum += __shfl_xor(ssum, off);
    float inv = 1.f / ssum;
    float2 o; o.x = g0 * inv; o.y = g1 * inv;
    *(float2*)(out + base) = o;
}

// ---------------------------------------------------------------------------
extern "C" void kernel_launch(void* const* d_in, const int* in_sizes, int n_in,
                              void* d_out, int out_size, void* d_ws, size_t ws_size,
                              hipStream_t stream) {
    const float* obs = (const float*)d_in[0];
    const float* trans = (const float*)d_in[1];
    const float* w1 = (const float*)d_in[2];
    const float* b1 = (const float*)d_in[3];
    const float* w2 = (const float*)d_in[4];
    const float* b2 = (const float*)d_in[5];

    char* ws = (char*)d_ws;
    float* PfT = (float*)(ws);                         // 64 KB
    float* PbT = (float*)(ws + 65536);                 // 64 KB
    ushort* w1b = (ushort*)(ws + 131072);              // 64 KB
    ushort* w2b = (ushort*)(ws + 196608);              // 128 KB
    ushort* emitb = (ushort*)(ws + 327680);            // 32 MB (E = exp(emit), bf16)
    float* galpha = (float*)(ws + 327680 + 33554432);  // 64 MB
    float* gbeta = (float*)(ws + 327680 + 33554432 + 67108864);  // 64 MB

    prep_trans<<<256, 128, 0, stream>>>(trans, PfT, PbT);
    conv_w<<<384, 256, 0, stream>>>(w1, w2, w1b, w2b);
    mlp_kernel<<<BB * (TT / MLP_ROWS), 512, 0, stream>>>(obs, w1b, w2b, b1, b2, emitb);
    scan_mfma<<<256, 256, 0, stream>>>(emitb, PfT, PbT, galpha, gbeta);
    combine_kernel<<<(BB * TT) / 4, 256, 0, stream>>>(galpha, gbeta, (float*)d_out);
}

// Round 7
// 182.212 us; speedup vs baseline: 2.6697x; 1.1609x over previous
//
#include <hip/hip_runtime.h>
#include <hip/hip_bf16.h>
#include <stdint.h>

#define BB 32
#define TT 4096
#define DD 64
#define SS 128
#define HH 512

#define SC_W 32
#define SC_L 32
// chains/(b,dir) = 128; 16 chains per WG; WGs = 32*2*8 = 512 (2 per CU)

typedef __attribute__((ext_vector_type(4))) float f32x4;
typedef __attribute__((ext_vector_type(8))) short s16x8;
typedef __attribute__((ext_vector_type(4))) short s16x4;

__device__ __forceinline__ ushort f2bfu(float x) {
    uint32_t b = __float_as_uint(x);
    uint32_t r = (b + 0x7FFFu + ((b >> 16) & 1u)) >> 16;
    return (ushort)r;
}
__device__ __forceinline__ float bfu2f(ushort u) {
    return __uint_as_float(((uint32_t)u) << 16);
}

// ---------------------------------------------------------------------------
// Prep: PfT[k][i] = softmax_row_i(trans)[k]; PbT[s][i] = softmax_col_i(trans)[s]
// ---------------------------------------------------------------------------
__global__ __launch_bounds__(128) void prep_trans(const float* __restrict__ tr,
                                                  float* __restrict__ PfT,
                                                  float* __restrict__ PbT) {
    int i = blockIdx.x & 127;
    int back = blockIdx.x >> 7;
    int j = threadIdx.x;
    float v = back ? tr[j * SS + i] : tr[i * SS + j];
    __shared__ float sh[4];
    float mx = v;
#pragma unroll
    for (int off = 32; off; off >>= 1) mx = fmaxf(mx, __shfl_xor(mx, off));
    if ((threadIdx.x & 63) == 0) sh[threadIdx.x >> 6] = mx;
    __syncthreads();
    mx = fmaxf(sh[0], sh[1]);
    float e = __expf(v - mx);
    float ssum = e;
#pragma unroll
    for (int off = 32; off; off >>= 1) ssum += __shfl_xor(ssum, off);
    if ((threadIdx.x & 63) == 0) sh[2 + (threadIdx.x >> 6)] = ssum;
    __syncthreads();
    float out = e / (sh[2] + sh[3]);
    if (back) PbT[j * SS + i] = out;
    else      PfT[j * SS + i] = out;
}

// ---------------------------------------------------------------------------
// Convert w1 (512x64) and w2 (128x512) fp32 -> bf16
// ---------------------------------------------------------------------------
__global__ void conv_w(const float* __restrict__ w1, const float* __restrict__ w2,
                       ushort* __restrict__ w1b, ushort* __restrict__ w2b) {
    int i = blockIdx.x * 256 + threadIdx.x;
    const int N1 = HH * DD;
    const int N2 = SS * HH;
    if (i < N1) w1b[i] = f2bfu(w1[i]);
    else if (i < N1 + N2) w2b[i - N1] = f2bfu(w2[i - N1]);
}

// ---------------------------------------------------------------------------
// Fused MLP: E[b][t][s] (bf16) = exp( relu(obs@W1^T + b1) @ W2^T + b2 )
// 64 t-rows per WG, 512 threads (8 waves).
// ---------------------------------------------------------------------------
#define MLP_ROWS 64
__global__ __launch_bounds__(512, 2) void mlp_kernel(
    const float* __restrict__ obs, const ushort* __restrict__ w1b,
    const ushort* __restrict__ w2b, const float* __restrict__ b1,
    const float* __restrict__ b2, ushort* __restrict__ emitb) {
    __shared__ __align__(16) ushort Alds[MLP_ROWS][72];
    __shared__ __align__(16) ushort Hlds[MLP_ROWS][524];

    int wg = blockIdx.x;                  // 32 * 64 = 2048
    int bb = wg >> 6;
    int t0 = (wg & 63) * MLP_ROWS;
    int tid = threadIdx.x;
    int lane = tid & 63, wv = tid >> 6;
    int lhi = lane >> 4, llo = lane & 15;

    {
        int r = tid >> 3, c0 = (tid & 7) * 8;
        const float* src = obs + ((size_t)bb * TT + t0 + r) * DD + c0;
        float4 v0 = *(const float4*)(src);
        float4 v1 = *(const float4*)(src + 4);
        s16x8 pk;
        pk[0] = (short)f2bfu(v0.x); pk[1] = (short)f2bfu(v0.y);
        pk[2] = (short)f2bfu(v0.z); pk[3] = (short)f2bfu(v0.w);
        pk[4] = (short)f2bfu(v1.x); pk[5] = (short)f2bfu(v1.y);
        pk[6] = (short)f2bfu(v1.z); pk[7] = (short)f2bfu(v1.w);
        *(s16x8*)(&Alds[r][c0]) = pk;
    }
    __syncthreads();

    f32x4 acc1[4][4];
#pragma unroll
    for (int mi = 0; mi < 4; ++mi)
#pragma unroll
        for (int ni = 0; ni < 4; ++ni) acc1[mi][ni] = (f32x4){0.f, 0.f, 0.f, 0.f};
    int nw0 = wv * 64;
#pragma unroll
    for (int kt = 0; kt < 2; ++kt) {
        s16x8 af[4];
#pragma unroll
        for (int mi = 0; mi < 4; ++mi)
            af[mi] = *(const s16x8*)(&Alds[mi * 16 + llo][kt * 32 + lhi * 8]);
#pragma unroll
        for (int ni = 0; ni < 4; ++ni) {
            int n = nw0 + ni * 16 + llo;
            s16x8 bf = *(const s16x8*)(w1b + n * DD + kt * 32 + lhi * 8);
#pragma unroll
            for (int mi = 0; mi < 4; ++mi)
                acc1[mi][ni] = __builtin_amdgcn_mfma_f32_16x16x32_bf16(af[mi], bf, acc1[mi][ni], 0, 0, 0);
        }
    }
#pragma unroll
    for (int ni = 0; ni < 4; ++ni) {
        int n = nw0 + ni * 16 + llo;
        float b1v = b1[n];
#pragma unroll
        for (int mi = 0; mi < 4; ++mi) {
#pragma unroll
            for (int r = 0; r < 4; ++r) {
                float hv = fmaxf(acc1[mi][ni][r] + b1v, 0.f);
                Hlds[mi * 16 + lhi * 4 + r][n] = f2bfu(hv);
            }
        }
    }
    __syncthreads();

    f32x4 acc2[4];
#pragma unroll
    for (int nt = 0; nt < 4; ++nt) acc2[nt] = (f32x4){0.f, 0.f, 0.f, 0.f};
    int s0 = wv * 16;
#pragma unroll
    for (int kt = 0; kt < 16; ++kt) {
        s16x8 wf = *(const s16x8*)(w2b + (s0 + llo) * HH + kt * 32 + lhi * 8);
#pragma unroll
        for (int nt = 0; nt < 4; ++nt) {
            s16x8 hf = *(const s16x8*)(&Hlds[nt * 16 + llo][kt * 32 + lhi * 8]);
            acc2[nt] = __builtin_amdgcn_mfma_f32_16x16x32_bf16(wf, hf, acc2[nt], 0, 0, 0);
        }
    }
    {
        int sbase = s0 + lhi * 4;
        float4 b2v = *(const float4*)(b2 + sbase);
#pragma unroll
        for (int nt = 0; nt < 4; ++nt) {
            int tl = nt * 16 + llo;
            ushort* dst = emitb + ((size_t)bb * TT + t0 + tl) * SS + sbase;
            s16x4 pk;
            pk[0] = (short)f2bfu(__expf(acc2[nt][0] + b2v.x));
            pk[1] = (short)f2bfu(__expf(acc2[nt][1] + b2v.y));
            pk[2] = (short)f2bfu(__expf(acc2[nt][2] + b2v.z));
            pk[3] = (short)f2bfu(__expf(acc2[nt][3] + b2v.w));
            *(s16x4*)dst = pk;
        }
    }
}

// ---------------------------------------------------------------------------
// MFMA-batched linear-space scan. L=32, W=32: 512 WGs (2/CU) x 64 steps.
// A-buffer packed: Apk[chain][state] = (bf16hi<<16)|bf16lo of p, unpacked
// with v_perm_b32 at read. Row stride 140 u32 (=12 mod 32).
// ---------------------------------------------------------------------------
__global__ __launch_bounds__(256, 2) void scan_mfma(
    const ushort* __restrict__ Eb, const float* __restrict__ PfT,
    const float* __restrict__ PbT, float* __restrict__ galpha,
    float* __restrict__ gbeta) {
    int wg = blockIdx.x;            // 32 b * 2 dir * 8 = 512
    int b = wg >> 4;
    int dir = (wg >> 3) & 1;
    int wgc = wg & 7;
    int resetRow = (dir == 0) ? (wgc == 0 ? 0 : -1) : (wgc == 7 ? 15 : -1);
    int tid = threadIdx.x;
    int l = tid & 63, w = tid >> 6;
    int l15 = l & 15, g = l >> 4;
    int d = dir ? -1 : 1;

    const float* PT = dir ? PbT : PfT;
    float* paB = (dir ? gbeta : galpha) + (size_t)b * TT * SS;
    const ushort* EbB = Eb + (size_t)b * TT * SS;

    int col0 = w * 32 + l15;
    int col1 = col0 + 16;

    // static B fragments: PT[s][k] split into bf16 hi + lo
    s16x8 Bhi[2][4], Blo[2][4];
#pragma unroll
    for (int tile = 0; tile < 2; ++tile) {
        int srow = w * 32 + tile * 16 + l15;
#pragma unroll
        for (int kt = 0; kt < 4; ++kt) {
            const float* src = PT + srow * SS + kt * 32 + g * 8;
            float x[8];
            *(float4*)(x) = *(const float4*)(src);
            *(float4*)(x + 4) = *(const float4*)(src + 4);
            s16x8 hi, lo;
#pragma unroll
            for (int j = 0; j < 8; ++j) {
                uint32_t bx = __float_as_uint(x[j]);
                uint32_t hb = bx & 0xFFFF0000u;
                float rem = x[j] - __uint_as_float(hb);
                hi[j] = (short)(hb >> 16);
                lo[j] = (short)f2bfu(rem);
            }
            Bhi[tile][kt] = hi; Blo[tile][kt] = lo;
        }
    }
#pragma unroll
    for (int tile = 0; tile < 2; ++tile)
#pragma unroll
        for (int kt = 0; kt < 4; ++kt) {
            asm volatile("" : "+v"(Bhi[tile][kt]));
            asm volatile("" : "+v"(Blo[tile][kt]));
        }

    __shared__ __align__(16) uint32_t Apk[2][16][140];
    __shared__ __align__(16) float mscale[2][16];

    // init p = 1.0 -> hi=0x3F80, lo=0 -> packed 0x3F800000
    for (int i = tid; i < 16 * 140; i += 256) (&Apk[0][0][0])[i] = 0x3F800000u;
    if (tid < 16) mscale[0][tid] = 1.0f;

    int tj[4];
#pragma unroll
    for (int j = 0; j < 4; ++j) {
        int chain = wgc * 16 + 4 * g + j;
        tj[j] = dir ? chain * SC_L + (SC_L - 1) + SC_W : chain * SC_L - SC_W;
    }

    __syncthreads();

    ushort EA[8], EB[8];
#pragma unroll
    for (int j = 0; j < 4; ++j) {
        int tc = tj[j] < 0 ? 0 : (tj[j] > TT - 1 ? TT - 1 : tj[j]);
        uint32_t ro = (uint32_t)tc << 7;
        EA[j] = EbB[ro + col0];
        EA[4 + j] = EbB[ro + col1];
    }

#define SCAN_STEP(VSTEP, par, EC, EN, DOSTORE, DORESET)                          \
    do {                                                                         \
        _Pragma("unroll") for (int j = 0; j < 4; ++j) {    /* E prefetch */      \
            int tn = tj[j] + d;                                                  \
            int tc = tn < 0 ? 0 : (tn > TT - 1 ? TT - 1 : tn);                   \
            uint32_t ro = (uint32_t)tc << 7;                                     \
            EN[j] = EbB[ro + col0];                                              \
            EN[4 + j] = EbB[ro + col1];                                          \
        }                                                                        \
        s16x8 ahi[4], alo[4];                                                    \
        _Pragma("unroll") for (int kt = 0; kt < 4; ++kt) {                       \
            uint4 ua = *(const uint4*)(&Apk[par][l15][kt * 32 + g * 8]);         \
            uint4 ub = *(const uint4*)(&Apk[par][l15][kt * 32 + g * 8 + 4]);     \
            uint4 hu, lu;                                                        \
            hu.x = __builtin_amdgcn_perm(ua.y, ua.x, 0x07060302u);               \
            hu.y = __builtin_amdgcn_perm(ua.w, ua.z, 0x07060302u);               \
            hu.z = __builtin_amdgcn_perm(ub.y, ub.x, 0x07060302u);               \
            hu.w = __builtin_amdgcn_perm(ub.w, ub.z, 0x07060302u);               \
            lu.x = __builtin_amdgcn_perm(ua.y, ua.x, 0x05040100u);               \
            lu.y = __builtin_amdgcn_perm(ua.w, ua.z, 0x05040100u);               \
            lu.z = __builtin_amdgcn_perm(ub.y, ub.x, 0x05040100u);               \
            lu.w = __builtin_amdgcn_perm(ub.w, ub.z, 0x05040100u);               \
            ahi[kt] = *(s16x8*)(&hu);                                            \
            alo[kt] = *(s16x8*)(&lu);                                            \
        }                                                                        \
        f32x4 rs = *(const f32x4*)(&mscale[par][4 * g]);                         \
        f32x4 aHH0 = {0,0,0,0}, aHL0 = {0,0,0,0}, aLH0 = {0,0,0,0};              \
        f32x4 aHH1 = {0,0,0,0}, aHL1 = {0,0,0,0}, aLH1 = {0,0,0,0};              \
        __builtin_amdgcn_s_setprio(1);                                           \
        _Pragma("unroll") for (int kt = 0; kt < 4; ++kt) {                       \
            aHH0 = __builtin_amdgcn_mfma_f32_16x16x32_bf16(ahi[kt], Bhi[0][kt], aHH0, 0, 0, 0); \
            aHH1 = __builtin_amdgcn_mfma_f32_16x16x32_bf16(ahi[kt], Bhi[1][kt], aHH1, 0, 0, 0); \
            aHL0 = __builtin_amdgcn_mfma_f32_16x16x32_bf16(ahi[kt], Blo[0][kt], aHL0, 0, 0, 0); \
            aHL1 = __builtin_amdgcn_mfma_f32_16x16x32_bf16(ahi[kt], Blo[1][kt], aHL1, 0, 0, 0); \
            aLH0 = __builtin_amdgcn_mfma_f32_16x16x32_bf16(alo[kt], Bhi[0][kt], aLH0, 0, 0, 0); \
            aLH1 = __builtin_amdgcn_mfma_f32_16x16x32_bf16(alo[kt], Bhi[1][kt], aLH1, 0, 0, 0); \
        }                                                                        \
        __builtin_amdgcn_s_setprio(0);                                           \
        f32x4 acc0 = (aHH0 + aHL0) + aLH0;                                       \
        f32x4 acc1 = (aHH1 + aHL1) + aLH1;                                       \
        float pv[8];                                                             \
        _Pragma("unroll") for (int j = 0; j < 4; ++j) {                          \
            pv[j] = acc0[j] * (bfu2f(EC[j]) * rs[j]);                            \
            pv[4 + j] = acc1[j] * (bfu2f(EC[4 + j]) * rs[j]);                    \
            if (DORESET && (VSTEP) == SC_W - 1 && resetRow == 4 * g + j) {       \
                pv[j] = 1.f; pv[4 + j] = 1.f;                                    \
            }                                                                    \
            if (DOSTORE) {                                                       \
                uint32_t po = (uint32_t)tj[j] << 7;                              \
                paB[po + col0] = pv[j];                                          \
                paB[po + col1] = pv[4 + j];                                      \
            }                                                                    \
            tj[j] += d;                                                          \
        }                                                                        \
        _Pragma("unroll") for (int j = 0; j < 4; ++j) {   /* write A(v+1) */     \
            int rr = 4 * g + j;                                                  \
            uint32_t b0 = __float_as_uint(pv[j]);                                \
            uint32_t h0 = b0 & 0xFFFF0000u;                                      \
            float r0 = pv[j] - __uint_as_float(h0);                              \
            Apk[(par) ^ 1][rr][col0] = h0 | (uint32_t)f2bfu(r0);                 \
            uint32_t b1 = __float_as_uint(pv[4 + j]);                            \
            uint32_t h1 = b1 & 0xFFFF0000u;                                      \
            float r1 = pv[4 + j] - __uint_as_float(h1);                          \
            Apk[(par) ^ 1][rr][col1] = h1 | (uint32_t)f2bfu(r1);                 \
        }                                                                        \
        if (w == 0 && l15 == 0) {                                                \
            f32x4 rn;                                                            \
            _Pragma("unroll") for (int j = 0; j < 4; ++j)                        \
                rn[j] = __builtin_amdgcn_rcpf(pv[j]);                            \
            *(f32x4*)(&mscale[(par) ^ 1][4 * g]) = rn;                           \
        }                                                                        \
        __builtin_amdgcn_sched_barrier(0);                                       \
        asm volatile("s_waitcnt lgkmcnt(0)" ::: "memory");                       \
        __builtin_amdgcn_s_barrier();                                            \
        __builtin_amdgcn_sched_barrier(0);                                       \
    } while (0)

    // warm: v = 0..31 (no stores; boundary chains reset at v=31)
    for (int v2 = 0; v2 < SC_W / 2; ++v2) {
        SCAN_STEP(2 * v2, 0, EA, EB, false, true);
        SCAN_STEP(2 * v2 + 1, 1, EB, EA, false, true);
    }
    // main: v = 32..63 (stores)
    for (int v2 = 0; v2 < SC_L / 2; ++v2) {
        SCAN_STEP(SC_W + 2 * v2, 0, EA, EB, true, false);
        SCAN_STEP(SC_W + 2 * v2 + 1, 1, EB, EA, true, false);
    }
#undef SCAN_STEP
}

// ---------------------------------------------------------------------------
// Combine (linear): out[b][t][s] = pa*pb / sum_s(pa*pb)
// ---------------------------------------------------------------------------
__global__ __launch_bounds__(256) void combine_kernel(
    const float* __restrict__ galpha, const float* __restrict__ gbeta,
    float* __restrict__ out) {
    int row = blockIdx.x * 4 + (threadIdx.x >> 6);
    int lane = threadIdx.x & 63;
    size_t base = (size_t)row * SS + lane * 2;
    float2 a = *(const float2*)(galpha + base);
    float2 b = *(const float2*)(gbeta + base);
    float g0 = a.x * b.x, g1 = a.y * b.y;
    float ssum = g0 + g1;
#pragma unroll
    for (int off = 32; off; off >>= 1) ssum += __shfl_xor(ssum, off);
    float inv = 1.f / ssum;
    float2 o; o.x = g0 * inv; o.y = g1 * inv;
    *(float2*)(out + base) = o;
}

// ---------------------------------------------------------------------------
extern "C" void kernel_launch(void* const* d_in, const int* in_sizes, int n_in,
                              void* d_out, int out_size, void* d_ws, size_t ws_size,
                              hipStream_t stream) {
    const float* obs = (const float*)d_in[0];
    const float* trans = (const float*)d_in[1];
    const float* w1 = (const float*)d_in[2];
    const float* b1 = (const float*)d_in[3];
    const float* w2 = (const float*)d_in[4];
    const float* b2 = (const float*)d_in[5];

    char* ws = (char*)d_ws;
    float* PfT = (float*)(ws);                         // 64 KB
    float* PbT = (float*)(ws + 65536);                 // 64 KB
    ushort* w1b = (ushort*)(ws + 131072);              // 64 KB
    ushort* w2b = (ushort*)(ws + 196608);              // 128 KB
    ushort* emitb = (ushort*)(ws + 327680);            // 32 MB (E = exp(emit), bf16)
    float* galpha = (float*)(ws + 327680 + 33554432);  // 64 MB
    float* gbeta = (float*)(ws + 327680 + 33554432 + 67108864);  // 64 MB

    prep_trans<<<256, 128, 0, stream>>>(trans, PfT, PbT);
    conv_w<<<384, 256, 0, stream>>>(w1, w2, w1b, w2b);
    mlp_kernel<<<BB * (TT / MLP_ROWS), 512, 0, stream>>>(obs, w1b, w2b, b1, b2, emitb);
    scan_mfma<<<BB * 2 * 8, 256, 0, stream>>>(emitb, PfT, PbT, galpha, gbeta);
    combine_kernel<<<(BB * TT) / 4, 256, 0, stream>>>(galpha, gbeta, (float*)d_out);
}